// Round 4
// baseline (491.622 us; speedup 1.0000x reference)
//
#include <hip/hip_runtime.h>
#include <cstdint>
#include <cstddef>

// B=4 S=2048 E=512 H=8 HD=64.
// G1 (x@Wqk) MX-scaled fp8 (16x16x128 f8f6f4, unit e8m0 scales). QK^T MX fp8
// (R1); R2: PV-before-QK + per-e sched_barrier fences (spill fix). R3:
// KV-split-2 flash — grid 512->1024 blocks (2->3 resident blocks/CU; occupancy
// was 21%, both pipes <30% = latency-bound). Fixed-shift softmax => partials
// combine linearly: blocks atomicAdd unnormalized O + row-sum l into f32
// oacc[8192][520] (cols 0..511 = O, col 512+h = l), normalize kernel emits
// bf16 vals. oacc overlays ws[0,17MB) (x_bf/x8/wqk8/wvt dead by flash time).
typedef unsigned short u16;
typedef unsigned char u8;
typedef long i64;                                        // 64-bit on amdgcn
typedef __attribute__((ext_vector_type(8))) short bh8;   // 8 bf16 (4 VGPR)
typedef __attribute__((ext_vector_type(4))) float fx4;   // 4 f32 acc
typedef __attribute__((ext_vector_type(8))) int i32x8;   // 32 fp8 (8 VGPR)

__device__ __forceinline__ u16 f2bf(float f) {           // RNE f32->bf16
  unsigned int u = __float_as_uint(f);
  u += 0x7fffu + ((u >> 16) & 1u);
  return (u16)(u >> 16);
}

// RNE f32 -> OCP e4m3fn, flush below 2^-6 to 0. Callers keep |f| in range.
__device__ __forceinline__ u8 f2e4m3(float f) {
  unsigned int u = __float_as_uint(f);
  unsigned int s = (u >> 24) & 0x80u;
  unsigned int mag = u & 0x7fffffffu;
  mag += 0x7ffffu + ((mag >> 20) & 1u);     // RNE at 3 mantissa bits
  if (mag < 0x3C800000u) return (u8)s;      // < 2^-6 -> signed zero
  unsigned int e8 = (mag >> 23) - 120u;     // bias 127 -> 7
  unsigned int m8 = (mag >> 20) & 7u;
  return (u8)(s | (e8 << 3) | m8);
}

typedef __attribute__((address_space(1))) void g1_void;
typedef __attribute__((address_space(3))) void l3_void;
__device__ __forceinline__ void gload_lds16(const void* g, const void* lds) {
  // async global->LDS, 16B/lane; LDS dest = wave-uniform base + lane*16
  __builtin_amdgcn_global_load_lds((g1_void*)(uintptr_t)g,
                                   (l3_void*)(unsigned int)(uintptr_t)lds,
                                   16, 0, 0);
}

__device__ __forceinline__ fx4 MFMA(bh8 a, bh8 b, fx4 c) {
  return __builtin_amdgcn_mfma_f32_16x16x32_bf16(a, b, c, 0, 0, 0);
}
// MX-scaled: K=128, A/B fmt = fp8 e4m3 (cbsz=0, blgp=0), scales = 1.0
// (e8m0 0x7F, byte 0). Lane layout: A[m=lane&15][k=(lane>>4)*32 + j], j<32.
__device__ __forceinline__ fx4 MFMAMX(i32x8 a, i32x8 b, fx4 c) {
  return __builtin_amdgcn_mfma_scale_f32_16x16x128_f8f6f4(a, b, c, 0, 0,
                                                          0, 0x7F, 0, 0x7F);
}
__device__ __forceinline__ i32x8 mk8(uint4 lo, uint4 hi) {
  i32x8 v;
  v[0] = (int)lo.x; v[1] = (int)lo.y; v[2] = (int)lo.z; v[3] = (int)lo.w;
  v[4] = (int)hi.x; v[5] = (int)hi.y; v[6] = (int)hi.z; v[7] = (int)hi.w;
  return v;
}

// ---------------- pre/post processing ----------------
// x f32 -> bf16 (for V-GEMM) and fp8 (for G1)
__global__ void cast_x2(const float* __restrict__ in, u16* __restrict__ outb,
                        u8* __restrict__ out8) {
  int i = blockIdx.x * 256 + threadIdx.x;           // grid sized exactly n/4
  float4 f = ((const float4*)in)[i];
  ushort4 u;
  u.x = f2bf(f.x); u.y = f2bf(f.y); u.z = f2bf(f.z); u.w = f2bf(f.w);
  ((ushort4*)outb)[i] = u;
  unsigned int p = (unsigned int)f2e4m3(f.x) | ((unsigned int)f2e4m3(f.y) << 8)
                 | ((unsigned int)f2e4m3(f.z) << 16) | ((unsigned int)f2e4m3(f.w) << 24);
  ((unsigned int*)out8)[i] = p;
}

// W[R][C] f32 -> Wt[C][R] bf16 (gemm_bt wants B as [N][K])
__global__ void tcast(const float* __restrict__ W, u16* __restrict__ Wt, int R, int C) {
  __shared__ float t[32][33];
  int tx = threadIdx.x, ty = threadIdx.y;
  int c0 = blockIdx.x * 32, r0 = blockIdx.y * 32;
#pragma unroll
  for (int i = 0; i < 4; i++)
    t[ty + i * 8][tx] = W[(size_t)(r0 + ty + i * 8) * C + c0 + tx];
  __syncthreads();
#pragma unroll
  for (int i = 0; i < 4; i++)
    Wt[(size_t)(c0 + ty + i * 8) * R + r0 + tx] = f2bf(t[tx][ty + i * 8]);
}

// W[R][C] f32 -> Wt[C][R] fp8, scaled x256 (exact pow2; descaled in GEMM)
__global__ void tcast8(const float* __restrict__ W, u8* __restrict__ Wt, int R, int C) {
  __shared__ float t[32][33];
  int tx = threadIdx.x, ty = threadIdx.y;
  int c0 = blockIdx.x * 32, r0 = blockIdx.y * 32;
#pragma unroll
  for (int i = 0; i < 4; i++)
    t[ty + i * 8][tx] = W[(size_t)(r0 + ty + i * 8) * C + c0 + tx];
  __syncthreads();
#pragma unroll
  for (int i = 0; i < 4; i++)
    Wt[(size_t)(c0 + ty + i * 8) * R + r0 + tx] = f2e4m3(t[tx][ty + i * 8] * 256.0f);
}

// zero the f32 accumulator region (8192*520 floats = 4160 blocks of 256 f4)
__global__ void zero_acc(float4* __restrict__ p) {
  p[blockIdx.x * 256 + threadIdx.x] = float4{0.f, 0.f, 0.f, 0.f};
}

// oacc[row][520] -> vals bf16 [row][512], divide by row/head sum at col 512+h
__global__ void norm_store(const float* __restrict__ oacc, u16* __restrict__ vals) {
  int idx = blockIdx.x * 256 + threadIdx.x;        // 8192*128 float4 cells
  int row = idx >> 7, c4 = (idx & 127) * 4;
  const float* rp = oacc + (size_t)row * 520;
  float4 o = *(const float4*)(rp + c4);
  float inv = 1.0f / rp[512 + (c4 >> 6)];
  ushort4 u;
  u.x = f2bf(o.x * inv); u.y = f2bf(o.y * inv);
  u.z = f2bf(o.z * inv); u.w = f2bf(o.w * inv);
  ((ushort4*)vals)[idx] = u;
}

// ---------------- GEMM bf16: C[M][N] = A[M][K] * Bt[N][K]^T + bias --------
// m97 structure: 128x128 tile, BK=64, 4 waves each 64x64 (4x4 of 16x16).
// OUT_MODE: 0 = f32, 1 = bf16, 3 = bf16 scattered as per-head V^T:
// vt[(b*512 + col)*2048 + s].
template <int OUT_MODE>
__global__ __launch_bounds__(256) void gemm_bt(const u16* __restrict__ A,
                                               const u16* __restrict__ Bt,
                                               const float* __restrict__ bias,
                                               void* __restrict__ Cout,
                                               int M, int N, int K) {
  __shared__ u16 As[128 * 64];
  __shared__ u16 Bs[128 * 64];
  const int tid = threadIdx.x;
  const int l = tid & 63, w = tid >> 6;
  const int lane15 = l & 15, quad = l >> 4;
  const int wm = (w >> 1) * 64, wn = (w & 1) * 64;
  const int bm = blockIdx.y * 128, bn = blockIdx.x * 128;
  fx4 acc[4][4] = {};

  const int srow = w * 32 + (l >> 3);
  const int scol = ((l & 7) ^ (l >> 3)) * 8;      // swizzle: slot (l&7) <- chunk (l&7)^(row&7)
  const u16* Ag = A + (size_t)(bm + srow) * K + scol;
  const u16* Bg = Bt + (size_t)(bn + srow) * K + scol;

  for (int kt = 0; kt < K; kt += 64) {
    __syncthreads();
#pragma unroll
    for (int c = 0; c < 4; c++) {
      gload_lds16(Ag + (size_t)(c * 8) * K + kt, As + (w * 32 + c * 8) * 64);
      gload_lds16(Bg + (size_t)(c * 8) * K + kt, Bs + (w * 32 + c * 8) * 64);
    }
    __syncthreads();
#pragma unroll
    for (int kk8 = 0; kk8 < 8; kk8 += 4) {        // kk8 = kk/8, kk in {0,32}
      bh8 a[4], b[4];
#pragma unroll
      for (int mi = 0; mi < 4; mi++) {
        int r = wm + mi * 16 + lane15;
        a[mi] = *(const bh8*)(As + r * 64 + (((kk8 + quad) ^ (r & 7)) * 8));
      }
#pragma unroll
      for (int ni = 0; ni < 4; ni++) {
        int r = wn + ni * 16 + lane15;
        b[ni] = *(const bh8*)(Bs + r * 64 + (((kk8 + quad) ^ (r & 7)) * 8));
      }
#pragma unroll
      for (int mi = 0; mi < 4; mi++)
#pragma unroll
        for (int ni = 0; ni < 4; ni++)
          acc[mi][ni] = MFMA(a[mi], b[ni], acc[mi][ni]);
    }
  }
  // epilogue: C/D layout col=lane&15, row=quad*4+reg  [measured m89/m91]
#pragma unroll
  for (int mi = 0; mi < 4; mi++)
#pragma unroll
    for (int ni = 0; ni < 4; ni++) {
      int col = bn + wn + ni * 16 + lane15;
      float bv = bias[col];
#pragma unroll
      for (int r = 0; r < 4; r++) {
        int row = bm + wm + mi * 16 + quad * 4 + r;
        float v = acc[mi][ni][r] + bv;
        if (OUT_MODE == 3)
          ((u16*)Cout)[((size_t)((row >> 11) * 512 + col) << 11) + (row & 2047)] = f2bf(v);
        else if (OUT_MODE == 1) ((u16*)Cout)[(size_t)row * N + col] = f2bf(v);
        else                    ((float*)Cout)[(size_t)row * N + col] = v;
      }
    }
}

// ---------------- GEMM fp8 MX: C = (A8 * B8t^T) * 2^-8 + bias -> fp8 -------
// m97 skeleton, BK=128 fp8, ONE 16x16x128 scaled MFMA per (mi,ni) per K-tile.
// Lane reads its 32 contiguous K bytes = two adjacent XOR-swizzled 16B slots.
__global__ __launch_bounds__(256) void gemm8_bt(const u8* __restrict__ A,
                                                const u8* __restrict__ Bt,
                                                const float* __restrict__ bias,
                                                u8* __restrict__ Cout,
                                                int M, int N, int K) {
  __shared__ u8 As[128 * 128];
  __shared__ u8 Bs[128 * 128];
  const int tid = threadIdx.x;
  const int l = tid & 63, w = tid >> 6;
  const int lane15 = l & 15, quad = l >> 4;
  const int wm = (w >> 1) * 64, wn = (w & 1) * 64;
  const int bm = blockIdx.y * 128, bn = blockIdx.x * 128;
  fx4 acc[4][4] = {};

  // staging: wave w covers rows w*32..+31 in 4 calls of 8 rows x 8 chunks
  const int srow = w * 32 + (l >> 3);
  const int scol = ((l & 7) ^ ((l >> 3) & 7)) * 16;
  const u8* Ag = A + (size_t)(bm + srow) * K + scol;
  const u8* Bg = Bt + (size_t)(bn + srow) * K + scol;

  const int q2 = quad * 2;             // first 16B chunk of this lane's 32B
  for (int kt = 0; kt < K; kt += 128) {
    __syncthreads();
#pragma unroll
    for (int c = 0; c < 4; c++) {
      gload_lds16(Ag + (size_t)(c * 8) * K + kt, As + (w * 32 + c * 8) * 128);
      gload_lds16(Bg + (size_t)(c * 8) * K + kt, Bs + (w * 32 + c * 8) * 128);
    }
    __syncthreads();
    i32x8 a[4], b[4];
#pragma unroll
    for (int mi = 0; mi < 4; mi++) {
      int r = wm + mi * 16 + lane15;
      const u8* rp = As + r * 128;
      a[mi] = mk8(*(const uint4*)(rp + ((q2 ^ (r & 7)) * 16)),
                  *(const uint4*)(rp + (((q2 + 1) ^ (r & 7)) * 16)));
    }
#pragma unroll
    for (int ni = 0; ni < 4; ni++) {
      int r = wn + ni * 16 + lane15;
      const u8* rp = Bs + r * 128;
      b[ni] = mk8(*(const uint4*)(rp + ((q2 ^ (r & 7)) * 16)),
                  *(const uint4*)(rp + (((q2 + 1) ^ (r & 7)) * 16)));
    }
#pragma unroll
    for (int mi = 0; mi < 4; mi++)
#pragma unroll
      for (int ni = 0; ni < 4; ni++)
        acc[mi][ni] = MFMAMX(a[mi], b[ni], acc[mi][ni]);
  }
  // epilogue: descale 2^-8 (W was quantized x256), add bias, store fp8
#pragma unroll
  for (int mi = 0; mi < 4; mi++)
#pragma unroll
    for (int ni = 0; ni < 4; ni++) {
      int col = bn + wn + ni * 16 + lane15;
      float bv = bias[col];
#pragma unroll
      for (int r = 0; r < 4; r++) {
        int row = bm + wm + mi * 16 + quad * 4 + r;
        Cout[(size_t)row * N + col] = f2e4m3(acc[mi][ni][r] * 0.00390625f + bv);
      }
    }
}

// ---------------- flash attention (KV-split-2) -----------------------------
// blockIdx.z = b*2 + sp; split sp handles K-tiles [sp*32, sp*32+32).
// Fixed-shift softmax (Mb const) => partial (accO, l) sums combine linearly
// across splits via f32 atomicAdd into oacc[8192][520]. R2 schedule kept:
// PV before QK, sched_barrier(0) per e-block (VGPR-liveness bound).
__global__ __launch_bounds__(256, 3) void flash_attn(const u8* __restrict__ qk8,
                                                     const u16* __restrict__ vt,
                                                     float* __restrict__ oacc) {
  __shared__ __align__(16) u8 Ks[2][32 * 512];   // 32KB fp8, chunk-swizzled
  __shared__ __align__(16) u16 Vs[2][64 * 40];   // 10KB bf16, padded rows
  __shared__ __align__(16) u16 Ps[4][32 * 40];   // 10KB per-wave P
  const int tid = threadIdx.x;
  const int l = tid & 63, w = tid >> 6;
  const int lane15 = l & 15, quad = l >> 4;
  const int q0 = blockIdx.x * 128;
  const int h = blockIdx.y;
  const int b = blockIdx.z >> 1, sp = blockIdx.z & 1;
  const int t0 = sp * 32;             // this split's first K-tile
  const float scale2 = 0.063762531f;   // (1/sqrt(512)) * log2(e)
  const float Mb = 2.0f;               // fixed shift (log2 domain)

  // Q in MX fragments: qmx[mt][e] = K bytes [e*128 + quad*32, +32) of the row
  i32x8 qmx[2][4];
#pragma unroll
  for (int mt = 0; mt < 2; mt++) {
    const u8* qrow = qk8 + (size_t)(b * 2048 + q0 + w * 32 + mt * 16 + lane15) * 8192
                   + h * 1024 + quad * 32;
#pragma unroll
    for (int e = 0; e < 4; e++)
      qmx[mt][e] = mk8(*(const uint4*)(qrow + e * 128),
                       *(const uint4*)(qrow + e * 128 + 16));
  }

  fx4 accO[2][4] = {};
  float lpart[2][4] = {};

  const u8* kbase = qk8 + (size_t)(b * 2048) * 8192 + h * 1024 + 512;
  const u16* vrow = vt + (size_t)((b * 8 + h) * 64 + (tid >> 2)) * 2048 + (tid & 3) * 8;
  const int vs_off = (tid >> 2) * 40 + (tid & 3) * 8;

  // prologue: stage Ks(t0); vreg holds V(t0)
  uint4 vreg = *(const uint4*)(vrow + t0 * 32);
#pragma unroll
  for (int c = 0; c < 4; c++) {
    int R0 = w * 8 + 2 * c;
    int r = R0 + (l >> 5);
    gload_lds16(kbase + (size_t)(t0 * 32 + r) * 8192 + (((l & 31) ^ (r & 7)) * 16),
                &Ks[0][R0 * 512]);
  }

  for (int t = t0; t < t0 + 32; t++) {
    const int cb = t & 1, nb = cb ^ 1;   // t0 even => cb==0 on first iter
    const int kt0 = t * 32;
    __syncthreads();                   // Ks(t)/Vs(t-1) landed; buffers free

    // PV(t-1) operands: issue early (latency hides under staging issue)
    bh8 pf0, pf1, vf0, vf1, vf2, vf3;
    if (t > t0) {
      const u16* vsb = &Vs[(t - 1) & 1][0];           // V(t-1)
      pf0 = *(const bh8*)(&Ps[w][lane15 * 40 + quad * 8]);
      pf1 = *(const bh8*)(&Ps[w][(16 + lane15) * 40 + quad * 8]);
      vf0 = *(const bh8*)(vsb + (lane15)      * 40 + quad * 8);
      vf1 = *(const bh8*)(vsb + (16 + lane15) * 40 + quad * 8);
      vf2 = *(const bh8*)(vsb + (32 + lane15) * 40 + quad * 8);
      vf3 = *(const bh8*)(vsb + (48 + lane15) * 40 + quad * 8);
    }

    *(uint4*)&Vs[cb][vs_off] = vreg;   // stage V(t) (read by PV at iter t+1)

    if (t < t0 + 31) {                 // stage Ks(t+1) (async DMA)
#pragma unroll
      for (int c = 0; c < 4; c++) {
        int R0 = w * 8 + 2 * c;
        int r = R0 + (l >> 5);
        gload_lds16(kbase + (size_t)(kt0 + 32 + r) * 8192 + (((l & 31) ^ (r & 7)) * 16),
                    &Ks[nb][R0 * 512]);
      }
      vreg = *(const uint4*)(vrow + kt0 + 32);        // V(t+1)
    }

    // PV(t-1): BEFORE QK so pf/vf registers die before the MX section
    if (t > t0) {
      accO[0][0] = MFMA(pf0, vf0, accO[0][0]); accO[1][0] = MFMA(pf1, vf0, accO[1][0]);
      accO[0][1] = MFMA(pf0, vf1, accO[0][1]); accO[1][1] = MFMA(pf1, vf1, accO[1][1]);
      accO[0][2] = MFMA(pf0, vf2, accO[0][2]); accO[1][2] = MFMA(pf1, vf2, accO[1][2]);
      accO[0][3] = MFMA(pf0, vf3, accO[0][3]); accO[1][3] = MFMA(pf1, vf3, accO[1][3]);
    }
    __builtin_amdgcn_sched_barrier(0);

    // S = Q*K^T: 32 q-rows x 32 k-cols per wave, E=512 inner, MX fp8 K=128.
    // sched_barrier(0) per e-block bounds live K fragments to one kb0/kb1
    // pair (16 VGPR) — prevents the hoist-all-loads schedule that spilled.
    fx4 accS[2][2] = {};
    {
      const int xsw = lane15 & 7;      // (16+lane15)&7 == lane15&7
      const u8* rp0 = &Ks[cb][lane15 * 512];
      const u8* rp1 = &Ks[cb][(16 + lane15) * 512];
#pragma unroll
      for (int e = 0; e < 4; e++) {
        int c0 = e * 8 + quad * 2;
        i32x8 kb0 = mk8(*(const uint4*)(rp0 + ((c0 ^ xsw) * 16)),
                        *(const uint4*)(rp0 + (((c0 + 1) ^ xsw) * 16)));
        i32x8 kb1 = mk8(*(const uint4*)(rp1 + ((c0 ^ xsw) * 16)),
                        *(const uint4*)(rp1 + (((c0 + 1) ^ xsw) * 16)));
        accS[0][0] = MFMAMX(qmx[0][e], kb0, accS[0][0]);
        accS[1][0] = MFMAMX(qmx[1][e], kb0, accS[1][0]);
        accS[0][1] = MFMAMX(qmx[0][e], kb1, accS[0][1]);
        accS[1][1] = MFMAMX(qmx[1][e], kb1, accS[1][1]);
        __builtin_amdgcn_sched_barrier(0);
      }
    }

    // fixed-shift exp (v_exp_f32 computes 2^x); store Ps(t) — no wait needed
#pragma unroll
    for (int mt = 0; mt < 2; mt++)
#pragma unroll
      for (int r = 0; r < 4; r++) {
        float p0 = __builtin_amdgcn_exp2f(__fmaf_rn(accS[mt][0][r], scale2, -Mb));
        float p1 = __builtin_amdgcn_exp2f(__fmaf_rn(accS[mt][1][r], scale2, -Mb));
        lpart[mt][r] += p0 + p1;
        Ps[w][(mt * 16 + quad * 4 + r) * 40 + lane15]      = f2bf(p0);
        Ps[w][(mt * 16 + quad * 4 + r) * 40 + 16 + lane15] = f2bf(p1);
      }
  }

  {  // tail: PV(last). V(t0+31) is in buffer (t0+31)&1 == 1 (both splits).
    const u16* vsb = &Vs[1][0];
    bh8 pf0 = *(const bh8*)(&Ps[w][lane15 * 40 + quad * 8]);
    bh8 pf1 = *(const bh8*)(&Ps[w][(16 + lane15) * 40 + quad * 8]);
#pragma unroll
    for (int di = 0; di < 4; di++) {
      bh8 vf = *(const bh8*)(vsb + (di * 16 + lane15) * 40 + quad * 8);
      accO[0][di] = MFMA(pf0, vf, accO[0][di]);
      accO[1][di] = MFMA(pf1, vf, accO[1][di]);
    }
  }

  // epilogue: row-sum across the 16 lanes, then atomic-accumulate partials
#pragma unroll
  for (int mt = 0; mt < 2; mt++)
#pragma unroll
    for (int r = 0; r < 4; r++) {
      float s = lpart[mt][r];
      s += __shfl_xor(s, 1);
      s += __shfl_xor(s, 2);
      s += __shfl_xor(s, 4);
      s += __shfl_xor(s, 8);
      int row = q0 + w * 32 + mt * 16 + quad * 4 + r;
      float* orow = oacc + (size_t)(b * 2048 + row) * 520 + h * 64 + lane15;
#pragma unroll
      for (int di = 0; di < 4; di++) atomicAdd(&orow[di * 16], accO[mt][di][r]);
      if (lane15 == 0)
        atomicAdd(oacc + (size_t)(b * 2048 + row) * 520 + 512 + h, s);
    }
}

// ---------------- launch ----------------
extern "C" void kernel_launch(void* const* d_in, const int* in_sizes, int n_in,
                              void* d_out, int out_size, void* d_ws, size_t ws_size,
                              hipStream_t stream) {
  const float* x   = (const float*)d_in[0];
  const float* Wqk = (const float*)d_in[1];
  const float* bqk = (const float*)d_in[2];
  const float* Wv  = (const float*)d_in[3];
  const float* bv  = (const float*)d_in[4];
  const float* Wo  = (const float*)d_in[5];
  const float* bo  = (const float*)d_in[6];
  float* out = (float*)d_out;

  char* ws = (char*)d_ws;                     // total use: ~97 MB
  u16* x_bf  = (u16*)(ws);                    // 8192x512 bf16 (8 MB)
  u8*  x8    = (u8*)(ws + 8388608);           // 8192x512 fp8  (4 MB)
  u8*  wqk8  = (u8*)(ws + 12582912);          // 8192x512 fp8  (4 MB)
  u16* wvt   = (u16*)(ws + 16777216);         // 512x512
  u16* wot   = (u16*)(ws + 17301504);         // 512x512
  u16* vtbuf = (u16*)(ws + 17825792);         // 32x64x2048 (per-head V^T)
  u16* valsb = (u16*)(ws + 26214400);         // 8192x512
  u8*  qk8   = (u8*)(ws + 34603008);          // 8192x8192 fp8 (64 MB)
  // oacc overlays [0, 17,039,360): x_bf/x8/wqk8/wvt — all dead before flash
  // (17,039,360 <= wot offset 17,301,504).
  float* oacc = (float*)(ws);                 // 8192x520 f32

  cast_x2<<<4096, 256, 0, stream>>>(x, x_bf, x8);
  tcast8<<<dim3(256, 16), dim3(32, 8), 0, stream>>>(Wqk, wqk8, 512, 8192);
  tcast<<<dim3(16, 16),  dim3(32, 8), 0, stream>>>(Wv, wvt, 512, 512);
  tcast<<<dim3(16, 16),  dim3(32, 8), 0, stream>>>(Wo, wot, 512, 512);

  gemm8_bt<<<dim3(64, 64), 256, 0, stream>>>(x8, wqk8, bqk, qk8, 8192, 8192, 512);
  gemm_bt<3><<<dim3(4, 64), 256, 0, stream>>>(x_bf, wvt, bv, vtbuf, 8192, 512, 512);

  zero_acc<<<4160, 256, 0, stream>>>((float4*)oacc);   // 8192*520 floats
  flash_attn<<<dim3(16, 8, 8), 256, 0, stream>>>(qk8, vtbuf, oacc);
  norm_store<<<4096, 256, 0, stream>>>(oacc, valsb);

  gemm_bt<0><<<dim3(4, 64), 256, 0, stream>>>(valsb, wot, bo, out, 8192, 512, 512);
}

// Round 5
// 373.068 us; speedup vs baseline: 1.3178x; 1.3178x over previous
//
#include <hip/hip_runtime.h>
#include <cstdint>
#include <cstddef>

// B=4 S=2048 E=512 H=8 HD=64.
// G1 (x@Wqk) MX-scaled fp8 (16x16x128 f8f6f4, unit e8m0 scales). QK^T MX fp8
// (R1); R2: PV-before-QK + per-e sched_barrier fences (spill fix; 124us
// flash, 297.8us total). R3 KV-split REVERTED (atomic combine +230MB HBM =
// +170us). R4: 2-deep kb software pipeline in the QK e-loop — e+1's 8
// ds_read_b128 issue before e's MFMAs inside each fenced block; +16 VGPR
// liveness, still under the launch_bounds(256,3) ~168 cap.
typedef unsigned short u16;
typedef unsigned char u8;
typedef long i64;                                        // 64-bit on amdgcn
typedef __attribute__((ext_vector_type(8))) short bh8;   // 8 bf16 (4 VGPR)
typedef __attribute__((ext_vector_type(4))) float fx4;   // 4 f32 acc
typedef __attribute__((ext_vector_type(8))) int i32x8;   // 32 fp8 (8 VGPR)

__device__ __forceinline__ u16 f2bf(float f) {           // RNE f32->bf16
  unsigned int u = __float_as_uint(f);
  u += 0x7fffu + ((u >> 16) & 1u);
  return (u16)(u >> 16);
}

// RNE f32 -> OCP e4m3fn, flush below 2^-6 to 0. Callers keep |f| in range.
__device__ __forceinline__ u8 f2e4m3(float f) {
  unsigned int u = __float_as_uint(f);
  unsigned int s = (u >> 24) & 0x80u;
  unsigned int mag = u & 0x7fffffffu;
  mag += 0x7ffffu + ((mag >> 20) & 1u);     // RNE at 3 mantissa bits
  if (mag < 0x3C800000u) return (u8)s;      // < 2^-6 -> signed zero
  unsigned int e8 = (mag >> 23) - 120u;     // bias 127 -> 7
  unsigned int m8 = (mag >> 20) & 7u;
  return (u8)(s | (e8 << 3) | m8);
}

typedef __attribute__((address_space(1))) void g1_void;
typedef __attribute__((address_space(3))) void l3_void;
__device__ __forceinline__ void gload_lds16(const void* g, const void* lds) {
  // async global->LDS, 16B/lane; LDS dest = wave-uniform base + lane*16
  __builtin_amdgcn_global_load_lds((g1_void*)(uintptr_t)g,
                                   (l3_void*)(unsigned int)(uintptr_t)lds,
                                   16, 0, 0);
}

__device__ __forceinline__ fx4 MFMA(bh8 a, bh8 b, fx4 c) {
  return __builtin_amdgcn_mfma_f32_16x16x32_bf16(a, b, c, 0, 0, 0);
}
// MX-scaled: K=128, A/B fmt = fp8 e4m3 (cbsz=0, blgp=0), scales = 1.0
// (e8m0 0x7F, byte 0). Lane layout: A[m=lane&15][k=(lane>>4)*32 + j], j<32.
__device__ __forceinline__ fx4 MFMAMX(i32x8 a, i32x8 b, fx4 c) {
  return __builtin_amdgcn_mfma_scale_f32_16x16x128_f8f6f4(a, b, c, 0, 0,
                                                          0, 0x7F, 0, 0x7F);
}
__device__ __forceinline__ i32x8 mk8(uint4 lo, uint4 hi) {
  i32x8 v;
  v[0] = (int)lo.x; v[1] = (int)lo.y; v[2] = (int)lo.z; v[3] = (int)lo.w;
  v[4] = (int)hi.x; v[5] = (int)hi.y; v[6] = (int)hi.z; v[7] = (int)hi.w;
  return v;
}

// ---------------- pre/post processing ----------------
// x f32 -> bf16 (for V-GEMM) and fp8 (for G1)
__global__ void cast_x2(const float* __restrict__ in, u16* __restrict__ outb,
                        u8* __restrict__ out8) {
  int i = blockIdx.x * 256 + threadIdx.x;           // grid sized exactly n/4
  float4 f = ((const float4*)in)[i];
  ushort4 u;
  u.x = f2bf(f.x); u.y = f2bf(f.y); u.z = f2bf(f.z); u.w = f2bf(f.w);
  ((ushort4*)outb)[i] = u;
  unsigned int p = (unsigned int)f2e4m3(f.x) | ((unsigned int)f2e4m3(f.y) << 8)
                 | ((unsigned int)f2e4m3(f.z) << 16) | ((unsigned int)f2e4m3(f.w) << 24);
  ((unsigned int*)out8)[i] = p;
}

// W[R][C] f32 -> Wt[C][R] bf16 (gemm_bt wants B as [N][K])
__global__ void tcast(const float* __restrict__ W, u16* __restrict__ Wt, int R, int C) {
  __shared__ float t[32][33];
  int tx = threadIdx.x, ty = threadIdx.y;
  int c0 = blockIdx.x * 32, r0 = blockIdx.y * 32;
#pragma unroll
  for (int i = 0; i < 4; i++)
    t[ty + i * 8][tx] = W[(size_t)(r0 + ty + i * 8) * C + c0 + tx];
  __syncthreads();
#pragma unroll
  for (int i = 0; i < 4; i++)
    Wt[(size_t)(c0 + ty + i * 8) * R + r0 + tx] = f2bf(t[tx][ty + i * 8]);
}

// W[R][C] f32 -> Wt[C][R] fp8, scaled x256 (exact pow2; descaled in GEMM)
__global__ void tcast8(const float* __restrict__ W, u8* __restrict__ Wt, int R, int C) {
  __shared__ float t[32][33];
  int tx = threadIdx.x, ty = threadIdx.y;
  int c0 = blockIdx.x * 32, r0 = blockIdx.y * 32;
#pragma unroll
  for (int i = 0; i < 4; i++)
    t[ty + i * 8][tx] = W[(size_t)(r0 + ty + i * 8) * C + c0 + tx];
  __syncthreads();
#pragma unroll
  for (int i = 0; i < 4; i++)
    Wt[(size_t)(c0 + ty + i * 8) * R + r0 + tx] = f2e4m3(t[tx][ty + i * 8] * 256.0f);
}

// ---------------- GEMM bf16: C[M][N] = A[M][K] * Bt[N][K]^T + bias --------
// m97 structure: 128x128 tile, BK=64, 4 waves each 64x64 (4x4 of 16x16).
// OUT_MODE: 0 = f32, 1 = bf16, 3 = bf16 scattered as per-head V^T:
// vt[(b*512 + col)*2048 + s].
template <int OUT_MODE>
__global__ __launch_bounds__(256) void gemm_bt(const u16* __restrict__ A,
                                               const u16* __restrict__ Bt,
                                               const float* __restrict__ bias,
                                               void* __restrict__ Cout,
                                               int M, int N, int K) {
  __shared__ u16 As[128 * 64];
  __shared__ u16 Bs[128 * 64];
  const int tid = threadIdx.x;
  const int l = tid & 63, w = tid >> 6;
  const int lane15 = l & 15, quad = l >> 4;
  const int wm = (w >> 1) * 64, wn = (w & 1) * 64;
  const int bm = blockIdx.y * 128, bn = blockIdx.x * 128;
  fx4 acc[4][4] = {};

  const int srow = w * 32 + (l >> 3);
  const int scol = ((l & 7) ^ (l >> 3)) * 8;      // swizzle: slot (l&7) <- chunk (l&7)^(row&7)
  const u16* Ag = A + (size_t)(bm + srow) * K + scol;
  const u16* Bg = Bt + (size_t)(bn + srow) * K + scol;

  for (int kt = 0; kt < K; kt += 64) {
    __syncthreads();
#pragma unroll
    for (int c = 0; c < 4; c++) {
      gload_lds16(Ag + (size_t)(c * 8) * K + kt, As + (w * 32 + c * 8) * 64);
      gload_lds16(Bg + (size_t)(c * 8) * K + kt, Bs + (w * 32 + c * 8) * 64);
    }
    __syncthreads();
#pragma unroll
    for (int kk8 = 0; kk8 < 8; kk8 += 4) {        // kk8 = kk/8, kk in {0,32}
      bh8 a[4], b[4];
#pragma unroll
      for (int mi = 0; mi < 4; mi++) {
        int r = wm + mi * 16 + lane15;
        a[mi] = *(const bh8*)(As + r * 64 + (((kk8 + quad) ^ (r & 7)) * 8));
      }
#pragma unroll
      for (int ni = 0; ni < 4; ni++) {
        int r = wn + ni * 16 + lane15;
        b[ni] = *(const bh8*)(Bs + r * 64 + (((kk8 + quad) ^ (r & 7)) * 8));
      }
#pragma unroll
      for (int mi = 0; mi < 4; mi++)
#pragma unroll
        for (int ni = 0; ni < 4; ni++)
          acc[mi][ni] = MFMA(a[mi], b[ni], acc[mi][ni]);
    }
  }
  // epilogue: C/D layout col=lane&15, row=quad*4+reg  [measured m89/m91]
#pragma unroll
  for (int mi = 0; mi < 4; mi++)
#pragma unroll
    for (int ni = 0; ni < 4; ni++) {
      int col = bn + wn + ni * 16 + lane15;
      float bv = bias[col];
#pragma unroll
      for (int r = 0; r < 4; r++) {
        int row = bm + wm + mi * 16 + quad * 4 + r;
        float v = acc[mi][ni][r] + bv;
        if (OUT_MODE == 3)
          ((u16*)Cout)[((size_t)((row >> 11) * 512 + col) << 11) + (row & 2047)] = f2bf(v);
        else if (OUT_MODE == 1) ((u16*)Cout)[(size_t)row * N + col] = f2bf(v);
        else                    ((float*)Cout)[(size_t)row * N + col] = v;
      }
    }
}

// ---------------- GEMM fp8 MX: C = (A8 * B8t^T) * 2^-8 + bias -> fp8 -------
// m97 skeleton, BK=128 fp8, ONE 16x16x128 scaled MFMA per (mi,ni) per K-tile.
// Lane reads its 32 contiguous K bytes = two adjacent XOR-swizzled 16B slots.
__global__ __launch_bounds__(256) void gemm8_bt(const u8* __restrict__ A,
                                                const u8* __restrict__ Bt,
                                                const float* __restrict__ bias,
                                                u8* __restrict__ Cout,
                                                int M, int N, int K) {
  __shared__ u8 As[128 * 128];
  __shared__ u8 Bs[128 * 128];
  const int tid = threadIdx.x;
  const int l = tid & 63, w = tid >> 6;
  const int lane15 = l & 15, quad = l >> 4;
  const int wm = (w >> 1) * 64, wn = (w & 1) * 64;
  const int bm = blockIdx.y * 128, bn = blockIdx.x * 128;
  fx4 acc[4][4] = {};

  // staging: wave w covers rows w*32..+31 in 4 calls of 8 rows x 8 chunks
  const int srow = w * 32 + (l >> 3);
  const int scol = ((l & 7) ^ ((l >> 3) & 7)) * 16;
  const u8* Ag = A + (size_t)(bm + srow) * K + scol;
  const u8* Bg = Bt + (size_t)(bn + srow) * K + scol;

  const int q2 = quad * 2;             // first 16B chunk of this lane's 32B
  for (int kt = 0; kt < K; kt += 128) {
    __syncthreads();
#pragma unroll
    for (int c = 0; c < 4; c++) {
      gload_lds16(Ag + (size_t)(c * 8) * K + kt, As + (w * 32 + c * 8) * 128);
      gload_lds16(Bg + (size_t)(c * 8) * K + kt, Bs + (w * 32 + c * 8) * 128);
    }
    __syncthreads();
    i32x8 a[4], b[4];
#pragma unroll
    for (int mi = 0; mi < 4; mi++) {
      int r = wm + mi * 16 + lane15;
      const u8* rp = As + r * 128;
      a[mi] = mk8(*(const uint4*)(rp + ((q2 ^ (r & 7)) * 16)),
                  *(const uint4*)(rp + (((q2 + 1) ^ (r & 7)) * 16)));
    }
#pragma unroll
    for (int ni = 0; ni < 4; ni++) {
      int r = wn + ni * 16 + lane15;
      const u8* rp = Bs + r * 128;
      b[ni] = mk8(*(const uint4*)(rp + ((q2 ^ (r & 7)) * 16)),
                  *(const uint4*)(rp + (((q2 + 1) ^ (r & 7)) * 16)));
    }
#pragma unroll
    for (int mi = 0; mi < 4; mi++)
#pragma unroll
      for (int ni = 0; ni < 4; ni++)
        acc[mi][ni] = MFMAMX(a[mi], b[ni], acc[mi][ni]);
  }
  // epilogue: descale 2^-8 (W was quantized x256), add bias, store fp8
#pragma unroll
  for (int mi = 0; mi < 4; mi++)
#pragma unroll
    for (int ni = 0; ni < 4; ni++) {
      int col = bn + wn + ni * 16 + lane15;
      float bv = bias[col];
#pragma unroll
      for (int r = 0; r < 4; r++) {
        int row = bm + wm + mi * 16 + quad * 4 + r;
        Cout[(size_t)row * N + col] = f2e4m3(acc[mi][ni][r] * 0.00390625f + bv);
      }
    }
}

// ---------------- flash attention ------------------------------------------
// QK^T = 16x mfma_scale_f32_16x16x128_f8f6f4 per t-iter (unit scales, math
// bit-identical to the MFMA8 chain). R2 schedule: PV before QK, fenced
// e-blocks. R4: 2-deep kb pipeline — e+1's ds_reads issue inside e's fenced
// block, before e's MFMAs; MFMAs of e wait only on loads issued at e-1.
__global__ __launch_bounds__(256, 3) void flash_attn(const u8* __restrict__ qk8,
                                                     const u16* __restrict__ vt,
                                                     u16* __restrict__ vals) {
  __shared__ __align__(16) u8 Ks[2][32 * 512];   // 32KB fp8, chunk-swizzled
  __shared__ __align__(16) u16 Vs[2][64 * 40];   // 10KB bf16, padded rows
  __shared__ __align__(16) u16 Ps[4][32 * 40];   // 10KB per-wave P
  const int tid = threadIdx.x;
  const int l = tid & 63, w = tid >> 6;
  const int lane15 = l & 15, quad = l >> 4;
  const int q0 = blockIdx.x * 128;
  const int h = blockIdx.y, b = blockIdx.z;
  const float scale2 = 0.063762531f;   // (1/sqrt(512)) * log2(e)
  const float Mb = 2.0f;               // fixed shift (log2 domain)

  // Q in MX fragments: qmx[mt][e] = K bytes [e*128 + quad*32, +32) of the row
  i32x8 qmx[2][4];
#pragma unroll
  for (int mt = 0; mt < 2; mt++) {
    const u8* qrow = qk8 + (size_t)(b * 2048 + q0 + w * 32 + mt * 16 + lane15) * 8192
                   + h * 1024 + quad * 32;
#pragma unroll
    for (int e = 0; e < 4; e++)
      qmx[mt][e] = mk8(*(const uint4*)(qrow + e * 128),
                       *(const uint4*)(qrow + e * 128 + 16));
  }

  fx4 accO[2][4] = {};
  float lpart[2][4] = {};

  const u8* kbase = qk8 + (size_t)(b * 2048) * 8192 + h * 1024 + 512;
  const u16* vrow = vt + (size_t)((b * 8 + h) * 64 + (tid >> 2)) * 2048 + (tid & 3) * 8;
  const int vs_off = (tid >> 2) * 40 + (tid & 3) * 8;

  // prologue: stage Ks(0); vreg holds V(0)
  uint4 vreg = *(const uint4*)vrow;
#pragma unroll
  for (int c = 0; c < 4; c++) {
    int R0 = w * 8 + 2 * c;
    int r = R0 + (l >> 5);
    gload_lds16(kbase + (size_t)r * 8192 + (((l & 31) ^ (r & 7)) * 16),
                &Ks[0][R0 * 512]);
  }

  for (int t = 0; t < 64; t++) {
    const int cb = t & 1, nb = cb ^ 1;
    const int kt0 = t * 32;
    __syncthreads();                   // Ks(t)/Vs(t-1) landed; buffers free

    // PV(t-1) operands: issue early (latency hides under staging issue)
    bh8 pf0, pf1, vf0, vf1, vf2, vf3;
    if (t > 0) {
      const u16* vsb = &Vs[(t - 1) & 1][0];           // V(t-1)
      pf0 = *(const bh8*)(&Ps[w][lane15 * 40 + quad * 8]);
      pf1 = *(const bh8*)(&Ps[w][(16 + lane15) * 40 + quad * 8]);
      vf0 = *(const bh8*)(vsb + (lane15)      * 40 + quad * 8);
      vf1 = *(const bh8*)(vsb + (16 + lane15) * 40 + quad * 8);
      vf2 = *(const bh8*)(vsb + (32 + lane15) * 40 + quad * 8);
      vf3 = *(const bh8*)(vsb + (48 + lane15) * 40 + quad * 8);
    }

    *(uint4*)&Vs[cb][vs_off] = vreg;   // stage V(t) (read by PV at iter t+1)

    if (t < 63) {                      // stage Ks(t+1) (async DMA)
#pragma unroll
      for (int c = 0; c < 4; c++) {
        int R0 = w * 8 + 2 * c;
        int r = R0 + (l >> 5);
        gload_lds16(kbase + (size_t)(kt0 + 32 + r) * 8192 + (((l & 31) ^ (r & 7)) * 16),
                    &Ks[nb][R0 * 512]);
      }
      vreg = *(const uint4*)(vrow + kt0 + 32);        // V(t+1)
    }

    // PV(t-1): BEFORE QK so pf/vf registers die before the MX section
    if (t > 0) {
      accO[0][0] = MFMA(pf0, vf0, accO[0][0]); accO[1][0] = MFMA(pf1, vf0, accO[1][0]);
      accO[0][1] = MFMA(pf0, vf1, accO[0][1]); accO[1][1] = MFMA(pf1, vf1, accO[1][1]);
      accO[0][2] = MFMA(pf0, vf2, accO[0][2]); accO[1][2] = MFMA(pf1, vf2, accO[1][2]);
      accO[0][3] = MFMA(pf0, vf3, accO[0][3]); accO[1][3] = MFMA(pf1, vf3, accO[1][3]);
    }
    __builtin_amdgcn_sched_barrier(0);

    // S = Q*K^T: 32 q-rows x 32 k-cols per wave, E=512 inner, MX fp8 K=128.
    // 2-deep kb pipeline: block e issues e+1's 8 ds_reads, then e's MFMAs
    // (waiting only on e-1's loads). Live kb = 2 pairs = 32 VGPR, bounded
    // by the per-block sched_barrier(0).
    fx4 accS[2][2] = {};
    {
      const int xsw = lane15 & 7;      // (16+lane15)&7 == lane15&7
      const u8* rp0 = &Ks[cb][lane15 * 512];
      const u8* rp1 = &Ks[cb][(16 + lane15) * 512];
      int c0 = quad * 2;               // e=0 chunks
      i32x8 kb0 = mk8(*(const uint4*)(rp0 + ((c0 ^ xsw) * 16)),
                      *(const uint4*)(rp0 + (((c0 + 1) ^ xsw) * 16)));
      i32x8 kb1 = mk8(*(const uint4*)(rp1 + ((c0 ^ xsw) * 16)),
                      *(const uint4*)(rp1 + (((c0 + 1) ^ xsw) * 16)));
#pragma unroll
      for (int e = 0; e < 4; e++) {
        i32x8 nb0, nb1;
        if (e < 3) {
          int c1 = (e + 1) * 8 + quad * 2;
          nb0 = mk8(*(const uint4*)(rp0 + ((c1 ^ xsw) * 16)),
                    *(const uint4*)(rp0 + (((c1 + 1) ^ xsw) * 16)));
          nb1 = mk8(*(const uint4*)(rp1 + ((c1 ^ xsw) * 16)),
                    *(const uint4*)(rp1 + (((c1 + 1) ^ xsw) * 16)));
        }
        accS[0][0] = MFMAMX(qmx[0][e], kb0, accS[0][0]);
        accS[1][0] = MFMAMX(qmx[1][e], kb0, accS[1][0]);
        accS[0][1] = MFMAMX(qmx[0][e], kb1, accS[0][1]);
        accS[1][1] = MFMAMX(qmx[1][e], kb1, accS[1][1]);
        __builtin_amdgcn_sched_barrier(0);
        if (e < 3) { kb0 = nb0; kb1 = nb1; }
      }
    }

    // fixed-shift exp (v_exp_f32 computes 2^x); store Ps(t) — no wait needed
#pragma unroll
    for (int mt = 0; mt < 2; mt++)
#pragma unroll
      for (int r = 0; r < 4; r++) {
        float p0 = __builtin_amdgcn_exp2f(__fmaf_rn(accS[mt][0][r], scale2, -Mb));
        float p1 = __builtin_amdgcn_exp2f(__fmaf_rn(accS[mt][1][r], scale2, -Mb));
        lpart[mt][r] += p0 + p1;
        Ps[w][(mt * 16 + quad * 4 + r) * 40 + lane15]      = f2bf(p0);
        Ps[w][(mt * 16 + quad * 4 + r) * 40 + 16 + lane15] = f2bf(p1);
      }
  }

  {  // tail: PV(63). V(63) is in buffer 63 & 1 == 1.
    const u16* vsb = &Vs[1][0];
    bh8 pf0 = *(const bh8*)(&Ps[w][lane15 * 40 + quad * 8]);
    bh8 pf1 = *(const bh8*)(&Ps[w][(16 + lane15) * 40 + quad * 8]);
#pragma unroll
    for (int di = 0; di < 4; di++) {
      bh8 vf = *(const bh8*)(vsb + (di * 16 + lane15) * 40 + quad * 8);
      accO[0][di] = MFMA(pf0, vf, accO[0][di]);
      accO[1][di] = MFMA(pf1, vf, accO[1][di]);
    }
  }

  // epilogue: reduce row-sums across the 16 lanes, normalize, store
#pragma unroll
  for (int mt = 0; mt < 2; mt++)
#pragma unroll
    for (int r = 0; r < 4; r++) {
      float s = lpart[mt][r];
      s += __shfl_xor(s, 1);
      s += __shfl_xor(s, 2);
      s += __shfl_xor(s, 4);
      s += __shfl_xor(s, 8);
      float inv = 1.0f / s;
      int row = q0 + w * 32 + mt * 16 + quad * 4 + r;
      u16* orow = vals + (size_t)(b * 2048 + row) * 512 + h * 64 + lane15;
#pragma unroll
      for (int di = 0; di < 4; di++) orow[di * 16] = f2bf(accO[mt][di][r] * inv);
    }
}

// ---------------- launch ----------------
extern "C" void kernel_launch(void* const* d_in, const int* in_sizes, int n_in,
                              void* d_out, int out_size, void* d_ws, size_t ws_size,
                              hipStream_t stream) {
  const float* x   = (const float*)d_in[0];
  const float* Wqk = (const float*)d_in[1];
  const float* bqk = (const float*)d_in[2];
  const float* Wv  = (const float*)d_in[3];
  const float* bv  = (const float*)d_in[4];
  const float* Wo  = (const float*)d_in[5];
  const float* bo  = (const float*)d_in[6];
  float* out = (float*)d_out;

  char* ws = (char*)d_ws;                     // total use: ~97 MB
  u16* x_bf  = (u16*)(ws);                    // 8192x512 bf16 (8 MB)
  u8*  x8    = (u8*)(ws + 8388608);           // 8192x512 fp8  (4 MB)
  u8*  wqk8  = (u8*)(ws + 12582912);          // 8192x512 fp8  (4 MB)
  u16* wvt   = (u16*)(ws + 16777216);         // 512x512
  u16* wot   = (u16*)(ws + 17301504);         // 512x512
  u16* vtbuf = (u16*)(ws + 17825792);         // 32x64x2048 (per-head V^T)
  u16* valsb = (u16*)(ws + 26214400);         // 8192x512
  u8*  qk8   = (u8*)(ws + 34603008);          // 8192x8192 fp8 (64 MB)

  cast_x2<<<4096, 256, 0, stream>>>(x, x_bf, x8);
  tcast8<<<dim3(256, 16), dim3(32, 8), 0, stream>>>(Wqk, wqk8, 512, 8192);
  tcast<<<dim3(16, 16),  dim3(32, 8), 0, stream>>>(Wv, wvt, 512, 512);
  tcast<<<dim3(16, 16),  dim3(32, 8), 0, stream>>>(Wo, wot, 512, 512);

  gemm8_bt<<<dim3(64, 64), 256, 0, stream>>>(x8, wqk8, bqk, qk8, 8192, 8192, 512);
  gemm_bt<3><<<dim3(4, 64), 256, 0, stream>>>(x_bf, wvt, bv, vtbuf, 8192, 512, 512);

  flash_attn<<<dim3(16, 8, 4), 256, 0, stream>>>(qk8, vtbuf, valsb);

  gemm_bt<0><<<dim3(4, 64), 256, 0, stream>>>(valsb, wot, bo, out, 8192, 512, 512);
}

// Round 6
// 268.901 us; speedup vs baseline: 1.8283x; 1.3874x over previous
//
#include <hip/hip_runtime.h>
#include <cstdint>
#include <cstddef>

// B=4 S=2048 E=512 H=8 HD=64.
// G1 (x@Wqk) MX-scaled fp8 (16x16x128 f8f6f4, unit e8m0 scales). QK^T MX fp8
// (R1); R2: PV-before-QK + per-e sched_barrier fences. R4 2-deep kb pipeline
// REVERTED (more spill: WRITE 11264->17920KB, flash 124->211us). R5:
// launch_bounds (256,3)->(256,2) — grid=512 gives only 2 blocks/CU anyway,
// so the 3-block register cap (~170 VGPR) only caused the residual 3MB
// spill (WRITE 11264 vs 8192 ideal). V<=256 now; residency unchanged.
typedef unsigned short u16;
typedef unsigned char u8;
typedef long i64;                                        // 64-bit on amdgcn
typedef __attribute__((ext_vector_type(8))) short bh8;   // 8 bf16 (4 VGPR)
typedef __attribute__((ext_vector_type(4))) float fx4;   // 4 f32 acc
typedef __attribute__((ext_vector_type(8))) int i32x8;   // 32 fp8 (8 VGPR)

__device__ __forceinline__ u16 f2bf(float f) {           // RNE f32->bf16
  unsigned int u = __float_as_uint(f);
  u += 0x7fffu + ((u >> 16) & 1u);
  return (u16)(u >> 16);
}

// RNE f32 -> OCP e4m3fn, flush below 2^-6 to 0. Callers keep |f| in range.
__device__ __forceinline__ u8 f2e4m3(float f) {
  unsigned int u = __float_as_uint(f);
  unsigned int s = (u >> 24) & 0x80u;
  unsigned int mag = u & 0x7fffffffu;
  mag += 0x7ffffu + ((mag >> 20) & 1u);     // RNE at 3 mantissa bits
  if (mag < 0x3C800000u) return (u8)s;      // < 2^-6 -> signed zero
  unsigned int e8 = (mag >> 23) - 120u;     // bias 127 -> 7
  unsigned int m8 = (mag >> 20) & 7u;
  return (u8)(s | (e8 << 3) | m8);
}

typedef __attribute__((address_space(1))) void g1_void;
typedef __attribute__((address_space(3))) void l3_void;
__device__ __forceinline__ void gload_lds16(const void* g, const void* lds) {
  // async global->LDS, 16B/lane; LDS dest = wave-uniform base + lane*16
  __builtin_amdgcn_global_load_lds((g1_void*)(uintptr_t)g,
                                   (l3_void*)(unsigned int)(uintptr_t)lds,
                                   16, 0, 0);
}

__device__ __forceinline__ fx4 MFMA(bh8 a, bh8 b, fx4 c) {
  return __builtin_amdgcn_mfma_f32_16x16x32_bf16(a, b, c, 0, 0, 0);
}
// MX-scaled: K=128, A/B fmt = fp8 e4m3 (cbsz=0, blgp=0), scales = 1.0
// (e8m0 0x7F, byte 0). Lane layout: A[m=lane&15][k=(lane>>4)*32 + j], j<32.
__device__ __forceinline__ fx4 MFMAMX(i32x8 a, i32x8 b, fx4 c) {
  return __builtin_amdgcn_mfma_scale_f32_16x16x128_f8f6f4(a, b, c, 0, 0,
                                                          0, 0x7F, 0, 0x7F);
}
__device__ __forceinline__ i32x8 mk8(uint4 lo, uint4 hi) {
  i32x8 v;
  v[0] = (int)lo.x; v[1] = (int)lo.y; v[2] = (int)lo.z; v[3] = (int)lo.w;
  v[4] = (int)hi.x; v[5] = (int)hi.y; v[6] = (int)hi.z; v[7] = (int)hi.w;
  return v;
}

// ---------------- pre/post processing ----------------
// x f32 -> bf16 (for V-GEMM) and fp8 (for G1)
__global__ void cast_x2(const float* __restrict__ in, u16* __restrict__ outb,
                        u8* __restrict__ out8) {
  int i = blockIdx.x * 256 + threadIdx.x;           // grid sized exactly n/4
  float4 f = ((const float4*)in)[i];
  ushort4 u;
  u.x = f2bf(f.x); u.y = f2bf(f.y); u.z = f2bf(f.z); u.w = f2bf(f.w);
  ((ushort4*)outb)[i] = u;
  unsigned int p = (unsigned int)f2e4m3(f.x) | ((unsigned int)f2e4m3(f.y) << 8)
                 | ((unsigned int)f2e4m3(f.z) << 16) | ((unsigned int)f2e4m3(f.w) << 24);
  ((unsigned int*)out8)[i] = p;
}

// W[R][C] f32 -> Wt[C][R] bf16 (gemm_bt wants B as [N][K])
__global__ void tcast(const float* __restrict__ W, u16* __restrict__ Wt, int R, int C) {
  __shared__ float t[32][33];
  int tx = threadIdx.x, ty = threadIdx.y;
  int c0 = blockIdx.x * 32, r0 = blockIdx.y * 32;
#pragma unroll
  for (int i = 0; i < 4; i++)
    t[ty + i * 8][tx] = W[(size_t)(r0 + ty + i * 8) * C + c0 + tx];
  __syncthreads();
#pragma unroll
  for (int i = 0; i < 4; i++)
    Wt[(size_t)(c0 + ty + i * 8) * R + r0 + tx] = f2bf(t[tx][ty + i * 8]);
}

// W[R][C] f32 -> Wt[C][R] fp8, scaled x256 (exact pow2; descaled in GEMM)
__global__ void tcast8(const float* __restrict__ W, u8* __restrict__ Wt, int R, int C) {
  __shared__ float t[32][33];
  int tx = threadIdx.x, ty = threadIdx.y;
  int c0 = blockIdx.x * 32, r0 = blockIdx.y * 32;
#pragma unroll
  for (int i = 0; i < 4; i++)
    t[ty + i * 8][tx] = W[(size_t)(r0 + ty + i * 8) * C + c0 + tx];
  __syncthreads();
#pragma unroll
  for (int i = 0; i < 4; i++)
    Wt[(size_t)(c0 + ty + i * 8) * R + r0 + tx] = f2e4m3(t[tx][ty + i * 8] * 256.0f);
}

// ---------------- GEMM bf16: C[M][N] = A[M][K] * Bt[N][K]^T + bias --------
// m97 structure: 128x128 tile, BK=64, 4 waves each 64x64 (4x4 of 16x16).
// OUT_MODE: 0 = f32, 1 = bf16, 3 = bf16 scattered as per-head V^T:
// vt[(b*512 + col)*2048 + s].
template <int OUT_MODE>
__global__ __launch_bounds__(256) void gemm_bt(const u16* __restrict__ A,
                                               const u16* __restrict__ Bt,
                                               const float* __restrict__ bias,
                                               void* __restrict__ Cout,
                                               int M, int N, int K) {
  __shared__ u16 As[128 * 64];
  __shared__ u16 Bs[128 * 64];
  const int tid = threadIdx.x;
  const int l = tid & 63, w = tid >> 6;
  const int lane15 = l & 15, quad = l >> 4;
  const int wm = (w >> 1) * 64, wn = (w & 1) * 64;
  const int bm = blockIdx.y * 128, bn = blockIdx.x * 128;
  fx4 acc[4][4] = {};

  const int srow = w * 32 + (l >> 3);
  const int scol = ((l & 7) ^ (l >> 3)) * 8;      // swizzle: slot (l&7) <- chunk (l&7)^(row&7)
  const u16* Ag = A + (size_t)(bm + srow) * K + scol;
  const u16* Bg = Bt + (size_t)(bn + srow) * K + scol;

  for (int kt = 0; kt < K; kt += 64) {
    __syncthreads();
#pragma unroll
    for (int c = 0; c < 4; c++) {
      gload_lds16(Ag + (size_t)(c * 8) * K + kt, As + (w * 32 + c * 8) * 64);
      gload_lds16(Bg + (size_t)(c * 8) * K + kt, Bs + (w * 32 + c * 8) * 64);
    }
    __syncthreads();
#pragma unroll
    for (int kk8 = 0; kk8 < 8; kk8 += 4) {        // kk8 = kk/8, kk in {0,32}
      bh8 a[4], b[4];
#pragma unroll
      for (int mi = 0; mi < 4; mi++) {
        int r = wm + mi * 16 + lane15;
        a[mi] = *(const bh8*)(As + r * 64 + (((kk8 + quad) ^ (r & 7)) * 8));
      }
#pragma unroll
      for (int ni = 0; ni < 4; ni++) {
        int r = wn + ni * 16 + lane15;
        b[ni] = *(const bh8*)(Bs + r * 64 + (((kk8 + quad) ^ (r & 7)) * 8));
      }
#pragma unroll
      for (int mi = 0; mi < 4; mi++)
#pragma unroll
        for (int ni = 0; ni < 4; ni++)
          acc[mi][ni] = MFMA(a[mi], b[ni], acc[mi][ni]);
    }
  }
  // epilogue: C/D layout col=lane&15, row=quad*4+reg  [measured m89/m91]
#pragma unroll
  for (int mi = 0; mi < 4; mi++)
#pragma unroll
    for (int ni = 0; ni < 4; ni++) {
      int col = bn + wn + ni * 16 + lane15;
      float bv = bias[col];
#pragma unroll
      for (int r = 0; r < 4; r++) {
        int row = bm + wm + mi * 16 + quad * 4 + r;
        float v = acc[mi][ni][r] + bv;
        if (OUT_MODE == 3)
          ((u16*)Cout)[((size_t)((row >> 11) * 512 + col) << 11) + (row & 2047)] = f2bf(v);
        else if (OUT_MODE == 1) ((u16*)Cout)[(size_t)row * N + col] = f2bf(v);
        else                    ((float*)Cout)[(size_t)row * N + col] = v;
      }
    }
}

// ---------------- GEMM fp8 MX: C = (A8 * B8t^T) * 2^-8 + bias -> fp8 -------
// m97 skeleton, BK=128 fp8, ONE 16x16x128 scaled MFMA per (mi,ni) per K-tile.
// Lane reads its 32 contiguous K bytes = two adjacent XOR-swizzled 16B slots.
__global__ __launch_bounds__(256) void gemm8_bt(const u8* __restrict__ A,
                                                const u8* __restrict__ Bt,
                                                const float* __restrict__ bias,
                                                u8* __restrict__ Cout,
                                                int M, int N, int K) {
  __shared__ u8 As[128 * 128];
  __shared__ u8 Bs[128 * 128];
  const int tid = threadIdx.x;
  const int l = tid & 63, w = tid >> 6;
  const int lane15 = l & 15, quad = l >> 4;
  const int wm = (w >> 1) * 64, wn = (w & 1) * 64;
  const int bm = blockIdx.y * 128, bn = blockIdx.x * 128;
  fx4 acc[4][4] = {};

  // staging: wave w covers rows w*32..+31 in 4 calls of 8 rows x 8 chunks
  const int srow = w * 32 + (l >> 3);
  const int scol = ((l & 7) ^ ((l >> 3) & 7)) * 16;
  const u8* Ag = A + (size_t)(bm + srow) * K + scol;
  const u8* Bg = Bt + (size_t)(bn + srow) * K + scol;

  const int q2 = quad * 2;             // first 16B chunk of this lane's 32B
  for (int kt = 0; kt < K; kt += 128) {
    __syncthreads();
#pragma unroll
    for (int c = 0; c < 4; c++) {
      gload_lds16(Ag + (size_t)(c * 8) * K + kt, As + (w * 32 + c * 8) * 128);
      gload_lds16(Bg + (size_t)(c * 8) * K + kt, Bs + (w * 32 + c * 8) * 128);
    }
    __syncthreads();
    i32x8 a[4], b[4];
#pragma unroll
    for (int mi = 0; mi < 4; mi++) {
      int r = wm + mi * 16 + lane15;
      const u8* rp = As + r * 128;
      a[mi] = mk8(*(const uint4*)(rp + ((q2 ^ (r & 7)) * 16)),
                  *(const uint4*)(rp + (((q2 + 1) ^ (r & 7)) * 16)));
    }
#pragma unroll
    for (int ni = 0; ni < 4; ni++) {
      int r = wn + ni * 16 + lane15;
      const u8* rp = Bs + r * 128;
      b[ni] = mk8(*(const uint4*)(rp + ((q2 ^ (r & 7)) * 16)),
                  *(const uint4*)(rp + (((q2 + 1) ^ (r & 7)) * 16)));
    }
#pragma unroll
    for (int mi = 0; mi < 4; mi++)
#pragma unroll
      for (int ni = 0; ni < 4; ni++)
        acc[mi][ni] = MFMAMX(a[mi], b[ni], acc[mi][ni]);
  }
  // epilogue: descale 2^-8 (W was quantized x256), add bias, store fp8
#pragma unroll
  for (int mi = 0; mi < 4; mi++)
#pragma unroll
    for (int ni = 0; ni < 4; ni++) {
      int col = bn + wn + ni * 16 + lane15;
      float bv = bias[col];
#pragma unroll
      for (int r = 0; r < 4; r++) {
        int row = bm + wm + mi * 16 + quad * 4 + r;
        Cout[(size_t)row * N + col] = f2e4m3(acc[mi][ni][r] * 0.00390625f + bv);
      }
    }
}

// ---------------- flash attention ------------------------------------------
// QK^T = 16x mfma_scale_f32_16x16x128_f8f6f4 per t-iter (unit scales, math
// bit-identical to the MFMA8 chain). R2 schedule: PV before QK, fenced
// e-blocks. R5: launch_bounds(256,2) — V<=256 kills the residual spill;
// residency stays 2 blocks/CU (grid=512 on 256 CUs is the binding limit).
__global__ __launch_bounds__(256, 2) void flash_attn(const u8* __restrict__ qk8,
                                                     const u16* __restrict__ vt,
                                                     u16* __restrict__ vals) {
  __shared__ __align__(16) u8 Ks[2][32 * 512];   // 32KB fp8, chunk-swizzled
  __shared__ __align__(16) u16 Vs[2][64 * 40];   // 10KB bf16, padded rows
  __shared__ __align__(16) u16 Ps[4][32 * 40];   // 10KB per-wave P
  const int tid = threadIdx.x;
  const int l = tid & 63, w = tid >> 6;
  const int lane15 = l & 15, quad = l >> 4;
  const int q0 = blockIdx.x * 128;
  const int h = blockIdx.y, b = blockIdx.z;
  const float scale2 = 0.063762531f;   // (1/sqrt(512)) * log2(e)
  const float Mb = 2.0f;               // fixed shift (log2 domain)

  // Q in MX fragments: qmx[mt][e] = K bytes [e*128 + quad*32, +32) of the row
  i32x8 qmx[2][4];
#pragma unroll
  for (int mt = 0; mt < 2; mt++) {
    const u8* qrow = qk8 + (size_t)(b * 2048 + q0 + w * 32 + mt * 16 + lane15) * 8192
                   + h * 1024 + quad * 32;
#pragma unroll
    for (int e = 0; e < 4; e++)
      qmx[mt][e] = mk8(*(const uint4*)(qrow + e * 128),
                       *(const uint4*)(qrow + e * 128 + 16));
  }

  fx4 accO[2][4] = {};
  float lpart[2][4] = {};

  const u8* kbase = qk8 + (size_t)(b * 2048) * 8192 + h * 1024 + 512;
  const u16* vrow = vt + (size_t)((b * 8 + h) * 64 + (tid >> 2)) * 2048 + (tid & 3) * 8;
  const int vs_off = (tid >> 2) * 40 + (tid & 3) * 8;

  // prologue: stage Ks(0); vreg holds V(0)
  uint4 vreg = *(const uint4*)vrow;
#pragma unroll
  for (int c = 0; c < 4; c++) {
    int R0 = w * 8 + 2 * c;
    int r = R0 + (l >> 5);
    gload_lds16(kbase + (size_t)r * 8192 + (((l & 31) ^ (r & 7)) * 16),
                &Ks[0][R0 * 512]);
  }

  for (int t = 0; t < 64; t++) {
    const int cb = t & 1, nb = cb ^ 1;
    const int kt0 = t * 32;
    __syncthreads();                   // Ks(t)/Vs(t-1) landed; buffers free

    // PV(t-1) operands: issue early (latency hides under staging issue)
    bh8 pf0, pf1, vf0, vf1, vf2, vf3;
    if (t > 0) {
      const u16* vsb = &Vs[(t - 1) & 1][0];           // V(t-1)
      pf0 = *(const bh8*)(&Ps[w][lane15 * 40 + quad * 8]);
      pf1 = *(const bh8*)(&Ps[w][(16 + lane15) * 40 + quad * 8]);
      vf0 = *(const bh8*)(vsb + (lane15)      * 40 + quad * 8);
      vf1 = *(const bh8*)(vsb + (16 + lane15) * 40 + quad * 8);
      vf2 = *(const bh8*)(vsb + (32 + lane15) * 40 + quad * 8);
      vf3 = *(const bh8*)(vsb + (48 + lane15) * 40 + quad * 8);
    }

    *(uint4*)&Vs[cb][vs_off] = vreg;   // stage V(t) (read by PV at iter t+1)

    if (t < 63) {                      // stage Ks(t+1) (async DMA)
#pragma unroll
      for (int c = 0; c < 4; c++) {
        int R0 = w * 8 + 2 * c;
        int r = R0 + (l >> 5);
        gload_lds16(kbase + (size_t)(kt0 + 32 + r) * 8192 + (((l & 31) ^ (r & 7)) * 16),
                    &Ks[nb][R0 * 512]);
      }
      vreg = *(const uint4*)(vrow + kt0 + 32);        // V(t+1)
    }

    // PV(t-1): BEFORE QK so pf/vf registers die before the MX section
    if (t > 0) {
      accO[0][0] = MFMA(pf0, vf0, accO[0][0]); accO[1][0] = MFMA(pf1, vf0, accO[1][0]);
      accO[0][1] = MFMA(pf0, vf1, accO[0][1]); accO[1][1] = MFMA(pf1, vf1, accO[1][1]);
      accO[0][2] = MFMA(pf0, vf2, accO[0][2]); accO[1][2] = MFMA(pf1, vf2, accO[1][2]);
      accO[0][3] = MFMA(pf0, vf3, accO[0][3]); accO[1][3] = MFMA(pf1, vf3, accO[1][3]);
    }
    __builtin_amdgcn_sched_barrier(0);

    // S = Q*K^T: 32 q-rows x 32 k-cols per wave, E=512 inner, MX fp8 K=128.
    // sched_barrier(0) per e-block bounds live K fragments to one kb0/kb1
    // pair (16 VGPR) — the verified R2 schedule.
    fx4 accS[2][2] = {};
    {
      const int xsw = lane15 & 7;      // (16+lane15)&7 == lane15&7
      const u8* rp0 = &Ks[cb][lane15 * 512];
      const u8* rp1 = &Ks[cb][(16 + lane15) * 512];
#pragma unroll
      for (int e = 0; e < 4; e++) {
        int c0 = e * 8 + quad * 2;
        i32x8 kb0 = mk8(*(const uint4*)(rp0 + ((c0 ^ xsw) * 16)),
                        *(const uint4*)(rp0 + (((c0 + 1) ^ xsw) * 16)));
        i32x8 kb1 = mk8(*(const uint4*)(rp1 + ((c0 ^ xsw) * 16)),
                        *(const uint4*)(rp1 + (((c0 + 1) ^ xsw) * 16)));
        accS[0][0] = MFMAMX(qmx[0][e], kb0, accS[0][0]);
        accS[1][0] = MFMAMX(qmx[1][e], kb0, accS[1][0]);
        accS[0][1] = MFMAMX(qmx[0][e], kb1, accS[0][1]);
        accS[1][1] = MFMAMX(qmx[1][e], kb1, accS[1][1]);
        __builtin_amdgcn_sched_barrier(0);
      }
    }

    // fixed-shift exp (v_exp_f32 computes 2^x); store Ps(t) — no wait needed
#pragma unroll
    for (int mt = 0; mt < 2; mt++)
#pragma unroll
      for (int r = 0; r < 4; r++) {
        float p0 = __builtin_amdgcn_exp2f(__fmaf_rn(accS[mt][0][r], scale2, -Mb));
        float p1 = __builtin_amdgcn_exp2f(__fmaf_rn(accS[mt][1][r], scale2, -Mb));
        lpart[mt][r] += p0 + p1;
        Ps[w][(mt * 16 + quad * 4 + r) * 40 + lane15]      = f2bf(p0);
        Ps[w][(mt * 16 + quad * 4 + r) * 40 + 16 + lane15] = f2bf(p1);
      }
  }

  {  // tail: PV(63). V(63) is in buffer 63 & 1 == 1.
    const u16* vsb = &Vs[1][0];
    bh8 pf0 = *(const bh8*)(&Ps[w][lane15 * 40 + quad * 8]);
    bh8 pf1 = *(const bh8*)(&Ps[w][(16 + lane15) * 40 + quad * 8]);
#pragma unroll
    for (int di = 0; di < 4; di++) {
      bh8 vf = *(const bh8*)(vsb + (di * 16 + lane15) * 40 + quad * 8);
      accO[0][di] = MFMA(pf0, vf, accO[0][di]);
      accO[1][di] = MFMA(pf1, vf, accO[1][di]);
    }
  }

  // epilogue: reduce row-sums across the 16 lanes, normalize, store
#pragma unroll
  for (int mt = 0; mt < 2; mt++)
#pragma unroll
    for (int r = 0; r < 4; r++) {
      float s = lpart[mt][r];
      s += __shfl_xor(s, 1);
      s += __shfl_xor(s, 2);
      s += __shfl_xor(s, 4);
      s += __shfl_xor(s, 8);
      float inv = 1.0f / s;
      int row = q0 + w * 32 + mt * 16 + quad * 4 + r;
      u16* orow = vals + (size_t)(b * 2048 + row) * 512 + h * 64 + lane15;
#pragma unroll
      for (int di = 0; di < 4; di++) orow[di * 16] = f2bf(accO[mt][di][r] * inv);
    }
}

// ---------------- launch ----------------
extern "C" void kernel_launch(void* const* d_in, const int* in_sizes, int n_in,
                              void* d_out, int out_size, void* d_ws, size_t ws_size,
                              hipStream_t stream) {
  const float* x   = (const float*)d_in[0];
  const float* Wqk = (const float*)d_in[1];
  const float* bqk = (const float*)d_in[2];
  const float* Wv  = (const float*)d_in[3];
  const float* bv  = (const float*)d_in[4];
  const float* Wo  = (const float*)d_in[5];
  const float* bo  = (const float*)d_in[6];
  float* out = (float*)d_out;

  char* ws = (char*)d_ws;                     // total use: ~97 MB
  u16* x_bf  = (u16*)(ws);                    // 8192x512 bf16 (8 MB)
  u8*  x8    = (u8*)(ws + 8388608);           // 8192x512 fp8  (4 MB)
  u8*  wqk8  = (u8*)(ws + 12582912);          // 8192x512 fp8  (4 MB)
  u16* wvt   = (u16*)(ws + 16777216);         // 512x512
  u16* wot   = (u16*)(ws + 17301504);         // 512x512
  u16* vtbuf = (u16*)(ws + 17825792);         // 32x64x2048 (per-head V^T)
  u16* valsb = (u16*)(ws + 26214400);         // 8192x512
  u8*  qk8   = (u8*)(ws + 34603008);          // 8192x8192 fp8 (64 MB)

  cast_x2<<<4096, 256, 0, stream>>>(x, x_bf, x8);
  tcast8<<<dim3(256, 16), dim3(32, 8), 0, stream>>>(Wqk, wqk8, 512, 8192);
  tcast<<<dim3(16, 16),  dim3(32, 8), 0, stream>>>(Wv, wvt, 512, 512);
  tcast<<<dim3(16, 16),  dim3(32, 8), 0, stream>>>(Wo, wot, 512, 512);

  gemm8_bt<<<dim3(64, 64), 256, 0, stream>>>(x8, wqk8, bqk, qk8, 8192, 8192, 512);
  gemm_bt<3><<<dim3(4, 64), 256, 0, stream>>>(x_bf, wvt, bv, vtbuf, 8192, 512, 512);

  flash_attn<<<dim3(16, 8, 4), 256, 0, stream>>>(qk8, vtbuf, valsb);

  gemm_bt<0><<<dim3(4, 64), 256, 0, stream>>>(valsb, wot, bo, out, 8192, 512, 512);
}